// Round 1
// baseline (145.386 us; speedup 1.0000x reference)
//
#include <hip/hip_runtime.h>
#include <stdint.h>

typedef unsigned int uint32;
typedef uint16_t u16;
typedef short short8 __attribute__((ext_vector_type(8)));
typedef float floatx4 __attribute__((ext_vector_type(4)));

#define BN_EPS 1e-5f

// wpack layout (in shorts): per (branch, tap, ci-chunk-of-64) a 128x64 bf16 block,
// rows of 128B, 16B slots pre-XOR-swizzled by (co&7).
#define OFF0 0
#define OFF1 32768
#define OFF2 327680
#define OFF3 622592
#define OFFP 917504
#define WPK_SHORTS 933888
#define U_B0 4096
#define U_B  36864
#define U_TOT 116736

__device__ __forceinline__ u16 f2bf(float f) {
  uint32 u = __float_as_uint(f);
  u += 0x7fffu + ((u >> 16) & 1u);
  return (u16)(u >> 16);
}

// ---------- prep 1: x fp32 -> bf16 ----------
__global__ void k_xcvt(const float* __restrict__ x, u16* __restrict__ xb, int n8) {
  int i = blockIdx.x * 256 + threadIdx.x;
  if (i >= n8) return;
  const floatx4* p = (const floatx4*)(x + (size_t)i * 8);
  floatx4 a = p[0], b = p[1];
  union { short8 s; u16 us[8]; } o;
  o.us[0]=f2bf(a[0]); o.us[1]=f2bf(a[1]); o.us[2]=f2bf(a[2]); o.us[3]=f2bf(a[3]);
  o.us[4]=f2bf(b[0]); o.us[5]=f2bf(b[1]); o.us[6]=f2bf(b[2]); o.us[7]=f2bf(b[3]);
  ((short8*)xb)[i] = o.s;
}

// ---------- prep 2: pack + swizzle weights to bf16 ----------
__global__ void k_wpack(const float* __restrict__ w0, const float* __restrict__ w1,
                        const float* __restrict__ w2, const float* __restrict__ w3,
                        const float* __restrict__ wp, u16* __restrict__ wpk) {
  int g = blockIdx.x * 256 + threadIdx.x;
  if (g >= U_TOT) return;
  const float* w; int Cin, t, q, u, off; bool k3;
  if (g < U_B0) {
    int blk = g >> 10; w = w0; Cin = 256; k3 = false; t = 0; q = blk; u = g & 1023;
    off = OFF0 + blk * 8192;
  } else if (g < U_B0 + U_B) {
    int g1 = g - U_B0; int blk = g1 >> 10; w = w1; Cin = 256; k3 = true;
    t = blk >> 2; q = blk & 3; u = g1 & 1023; off = OFF1 + blk * 8192;
  } else if (g < U_B0 + 2*U_B) {
    int g1 = g - (U_B0 + U_B); int blk = g1 >> 10; w = w2; Cin = 256; k3 = true;
    t = blk >> 2; q = blk & 3; u = g1 & 1023; off = OFF2 + blk * 8192;
  } else if (g < U_B0 + 3*U_B) {
    int g1 = g - (U_B0 + 2*U_B); int blk = g1 >> 10; w = w3; Cin = 256; k3 = true;
    t = blk >> 2; q = blk & 3; u = g1 & 1023; off = OFF3 + blk * 8192;
  } else {
    int g1 = g - (U_B0 + 3*U_B); int blk = g1 >> 10; w = wp; Cin = 128; k3 = false;
    t = 0; q = blk; u = g1 & 1023; off = OFFP + blk * 8192;
  }
  int co = u >> 3, slot = u & 7;
  int sl = slot ^ (co & 7);           // logical 8-ci chunk stored at this physical slot
  int ci0 = q * 64 + sl * 8;
  int kh = k3 ? (t / 3) : 0, kw = k3 ? (t % 3) : 0;
  union { short8 s; u16 us[8]; } v;
  #pragma unroll
  for (int e = 0; e < 8; ++e) {
    int ci = ci0 + e;
    float wv = k3 ? w[((co * Cin + ci) * 3 + kh) * 3 + kw] : w[co * Cin + ci];
    v.us[e] = f2bf(wv);
  }
  *(short8*)(wpk + off + u * 8) = v.s;
}

// ---------- prep 3: BN scale/shift ----------
__global__ void k_bn(const float* g0,const float* b0,const float* m0,const float* v0,
                     const float* g1,const float* b1,const float* m1,const float* v1,
                     const float* g2,const float* b2,const float* m2,const float* v2,
                     const float* g3,const float* b3,const float* m3,const float* v3,
                     const float* gp,const float* bp,const float* mp,const float* vp,
                     float* __restrict__ bn) {
  int i = blockIdx.x * 256 + threadIdx.x;
  if (i >= 640) return;
  int t = i >> 7, co = i & 127;
  const float *G, *B, *M, *V;
  if      (t == 0) { G=g0; B=b0; M=m0; V=v0; }
  else if (t == 1) { G=g1; B=b1; M=m1; V=v1; }
  else if (t == 2) { G=g2; B=b2; M=m2; V=v2; }
  else if (t == 3) { G=g3; B=b3; M=m3; V=v3; }
  else             { G=gp; B=bp; M=mp; V=vp; }
  float s = G[co] * rsqrtf(V[co] + BN_EPS);
  bn[t * 256 + co]       = s;
  bn[t * 256 + 128 + co] = B[co] - M[co] * s;
}

// ---------- main: fused branch-conv + BN/ReLU + projection + BN/ReLU ----------
__global__ __launch_bounds__(256, 2)
void k_main(const u16* __restrict__ xb, const u16* __restrict__ wpk,
            const float* __restrict__ bn, float* __restrict__ out) {
  __shared__ __align__(16) u16 As[8192];    // 128 co x 64 k, swizzled by (co&7)
  __shared__ __align__(16) u16 Bs[8192];    // 128 px x 64 k, swizzled by ((px>>1)&7)
  __shared__ __align__(16) u16 Ps[16384];   // 128 px x 128 ci, swizzled by ((px>>1)&7)

  int tid = threadIdx.x;
  int bid = blockIdx.x;
  int tile = bid & 31, b = (bid >> 5) & 3, n = bid >> 7;
  int i0 = tile * 2;
  int lane = tid & 63, wid = tid >> 6;
  int wm = wid >> 1, wn = wid & 1;
  int m16 = lane & 15, hh = lane >> 4;

  const u16* xg = xb + (size_t)n * (256 * 4096);
  int d = (b == 0) ? 0 : ((b == 1) ? 6 : ((b == 2) ? 12 : 18));
  int T = (b == 0) ? 1 : 9;
  int woff8 = ((b == 0) ? OFF0 : (b == 1) ? OFF1 : (b == 2) ? OFF2 : OFF3) / 8;

  const short8* wpk8 = (const short8*)wpk;
  short8* AsS8 = (short8*)As;
  short8* BsS8 = (short8*)Bs;
  const short8* PsS8 = (const short8*)Ps;

  floatx4 acc[4][4];
  #pragma unroll
  for (int a1 = 0; a1 < 4; ++a1)
    #pragma unroll
    for (int a2 = 0; a2 < 4; ++a2) acc[a1][a2] = (floatx4){0.f, 0.f, 0.f, 0.f};

  for (int t = 0; t < T; ++t) {
    int di = d * (t / 3 - 1);
    int dj = d * (t % 3 - 1);
    for (int q = 0; q < 4; ++q) {
      __syncthreads();
      // stage A (16KB linear copy, pre-swizzled in wpack)
      int abase = woff8 + (t * 4 + q) * 1024;
      #pragma unroll
      for (int w = 0; w < 4; ++w) AsS8[w * 256 + tid] = wpk8[abase + w * 256 + tid];
      // stage B (im2col gather: 8 ci per lane, px-pair via dword loads)
      #pragma unroll
      for (int pu = 0; pu < 2; ++pu) {
        int pidx = pu * 256 + tid;
        int cg = pidx >> 6;                 // 0..7
        int pp = pidx & 63;
        int row = pp >> 5;                  // 0..1
        int col0 = (pp & 31) * 2;           // even column
        int px0 = row * 64 + col0;
        int ii = i0 + row + di;
        int jj = col0 + dj;                 // even (d even) -> pair shares bounds
        bool inb = (ii >= 0) && (ii < 64) && (jj >= 0) && (jj < 64);
        int rel = ii * 64 + jj;
        size_t offs = inb ? ((size_t)(q * 64 + cg * 8) * 4096 + rel) : 0;
        const u16* src = xg + offs;
        union { short8 s; u16 us[8]; } lo, hi;
        #pragma unroll
        for (int e = 0; e < 8; ++e) {
          uint32 vv = *(const uint32*)(src + (size_t)e * 4096);
          vv = inb ? vv : 0u;
          lo.us[e] = (u16)(vv & 0xffffu);
          hi.us[e] = (u16)(vv >> 16);
        }
        int sw = (px0 >> 1) & 7;
        BsS8[px0 * 8 + (cg ^ sw)] = lo.s;
        BsS8[(px0 + 1) * 8 + (cg ^ sw)] = hi.s;
      }
      __syncthreads();
      // MFMA: 2 k-halves of 32
      #pragma unroll
      for (int kk = 0; kk < 2; ++kk) {
        short8 af[4], bfr[4];
        #pragma unroll
        for (int f = 0; f < 4; ++f) {
          int row = wm * 64 + f * 16 + m16;
          af[f] = AsS8[row * 8 + ((kk * 4 + hh) ^ (row & 7))];
        }
        #pragma unroll
        for (int f = 0; f < 4; ++f) {
          int px = wn * 64 + f * 16 + m16;
          bfr[f] = BsS8[px * 8 + ((kk * 4 + hh) ^ ((px >> 1) & 7))];
        }
        #pragma unroll
        for (int fm = 0; fm < 4; ++fm)
          #pragma unroll
          for (int fn = 0; fn < 4; ++fn)
            acc[fm][fn] = __builtin_amdgcn_mfma_f32_16x16x32_bf16(
                af[fm], bfr[fn], acc[fm][fn], 0, 0, 0);
      }
    }
  }

  // branch BN + ReLU -> Ps (bf16), layout [px][ci] swizzled
  #pragma unroll
  for (int fm = 0; fm < 4; ++fm) {
    #pragma unroll
    for (int r = 0; r < 4; ++r) {
      int co = wm * 64 + fm * 16 + hh * 4 + r;
      float s  = bn[b * 256 + co];
      float sh = bn[b * 256 + 128 + co];
      #pragma unroll
      for (int fn = 0; fn < 4; ++fn) {
        int px = wn * 64 + fn * 16 + m16;
        float v = fmaxf(acc[fm][fn][r] * s + sh, 0.f);
        Ps[px * 128 + (((co >> 3) ^ ((px >> 1) & 7)) << 3) + (co & 7)] = f2bf(v);
      }
    }
  }

  // projection GEMM: out128 x px128, K=128
  floatx4 acc2[4][4];
  #pragma unroll
  for (int a1 = 0; a1 < 4; ++a1)
    #pragma unroll
    for (int a2 = 0; a2 < 4; ++a2) acc2[a1][a2] = (floatx4){0.f, 0.f, 0.f, 0.f};

  for (int q = 0; q < 2; ++q) {
    __syncthreads();   // Ps written (q=0) / As reads done (q=1)
    int abase = OFFP / 8 + q * 1024;
    #pragma unroll
    for (int w = 0; w < 4; ++w) AsS8[w * 256 + tid] = wpk8[abase + w * 256 + tid];
    __syncthreads();
    #pragma unroll
    for (int kk = 0; kk < 2; ++kk) {
      short8 af[4], bfr[4];
      #pragma unroll
      for (int f = 0; f < 4; ++f) {
        int row = wm * 64 + f * 16 + m16;
        af[f] = AsS8[row * 8 + ((kk * 4 + hh) ^ (row & 7))];
      }
      #pragma unroll
      for (int f = 0; f < 4; ++f) {
        int px = wn * 64 + f * 16 + m16;
        int slot = q * 8 + kk * 4 + hh;
        bfr[f] = PsS8[px * 16 + (slot ^ ((px >> 1) & 7))];
      }
      #pragma unroll
      for (int fm = 0; fm < 4; ++fm)
        #pragma unroll
        for (int fn = 0; fn < 4; ++fn)
          acc2[fm][fn] = __builtin_amdgcn_mfma_f32_16x16x32_bf16(
              af[fm], bfr[fn], acc2[fm][fn], 0, 0, 0);
    }
  }

  // proj BN + ReLU -> interleaved store
  int rb = b >> 1, cb = b & 1;
  #pragma unroll
  for (int fm = 0; fm < 4; ++fm) {
    #pragma unroll
    for (int r = 0; r < 4; ++r) {
      int co = wm * 64 + fm * 16 + hh * 4 + r;
      float s  = bn[1024 + co];
      float sh = bn[1024 + 128 + co];
      #pragma unroll
      for (int fn = 0; fn < 4; ++fn) {
        int px = wn * 64 + fn * 16 + m16;
        int i = i0 + (px >> 6), j = px & 63;
        float v = fmaxf(acc2[fm][fn][r] * s + sh, 0.f);
        out[(((n * 128 + co) * 128) + (2 * i + rb)) * 128 + (2 * j + cb)] = v;
      }
    }
  }
}

extern "C" void kernel_launch(void* const* d_in, const int* in_sizes, int n_in,
                              void* d_out, int out_size, void* d_ws, size_t ws_size,
                              hipStream_t stream) {
  const float* x  = (const float*)d_in[0];
  const float* w0 = (const float*)d_in[1];
  const float* w1 = (const float*)d_in[2];
  const float* w2 = (const float*)d_in[3];
  const float* w3 = (const float*)d_in[4];
  const float* wp = (const float*)d_in[5];

  u16* xbuf = (u16*)d_ws;                              // 8,388,608 shorts = 16 MiB
  u16* wpk  = (u16*)d_ws + 8388608;                    // 933,888 shorts
  float* bn = (float*)((char*)d_ws + 16777216 + 1867776);  // 5*256 floats

  k_xcvt<<<4096, 256, 0, stream>>>(x, xbuf, 1048576);
  k_wpack<<<456, 256, 0, stream>>>(w0, w1, w2, w3, wp, wpk);
  k_bn<<<3, 256, 0, stream>>>(
      (const float*)d_in[6],  (const float*)d_in[7],  (const float*)d_in[8],  (const float*)d_in[9],
      (const float*)d_in[10], (const float*)d_in[11], (const float*)d_in[12], (const float*)d_in[13],
      (const float*)d_in[14], (const float*)d_in[15], (const float*)d_in[16], (const float*)d_in[17],
      (const float*)d_in[18], (const float*)d_in[19], (const float*)d_in[20], (const float*)d_in[21],
      (const float*)d_in[22], (const float*)d_in[23], (const float*)d_in[24], (const float*)d_in[25],
      bn);
  k_main<<<1024, 256, 0, stream>>>(xbuf, wpk, bn, (float*)d_out);
}

// Round 3
// 121.018 us; speedup vs baseline: 1.2014x; 1.2014x over previous
//
#include <hip/hip_runtime.h>
#include <stdint.h>

typedef unsigned int uint32;
typedef uint16_t u16;
typedef short short8 __attribute__((ext_vector_type(8)));
typedef short shortx4 __attribute__((ext_vector_type(4)));
typedef float floatx4 __attribute__((ext_vector_type(4)));

#define BN_EPS 1e-5f

// wpack layout (in shorts): per (branch, tap, ci-chunk-of-64) a 128x64 bf16 block,
// rows of 128B, 16B slots pre-XOR-swizzled by (co&7).
#define OFF0 0
#define OFF1 32768
#define OFF2 327680
#define OFF3 622592
#define OFFP 917504
#define WPK_SHORTS 933888
#define U_B0 4096
#define U_B  36864
#define U_TOT 116736

__device__ __forceinline__ u16 f2bf(float f) {
  uint32 u = __float_as_uint(f);
  u += 0x7fffu + ((u >> 16) & 1u);
  return (u16)(u >> 16);
}

// ---------- prep 1: x fp32 -> bf16 ----------
__global__ void k_xcvt(const float* __restrict__ x, u16* __restrict__ xb, int n8) {
  int i = blockIdx.x * 256 + threadIdx.x;
  if (i >= n8) return;
  const floatx4* p = (const floatx4*)(x + (size_t)i * 8);
  floatx4 a = p[0], b = p[1];
  union { short8 s; u16 us[8]; } o;
  o.us[0]=f2bf(a[0]); o.us[1]=f2bf(a[1]); o.us[2]=f2bf(a[2]); o.us[3]=f2bf(a[3]);
  o.us[4]=f2bf(b[0]); o.us[5]=f2bf(b[1]); o.us[6]=f2bf(b[2]); o.us[7]=f2bf(b[3]);
  ((short8*)xb)[i] = o.s;
}

// ---------- prep 2: pack + swizzle weights to bf16 ----------
__global__ void k_wpack(const float* __restrict__ w0, const float* __restrict__ w1,
                        const float* __restrict__ w2, const float* __restrict__ w3,
                        const float* __restrict__ wp, u16* __restrict__ wpk) {
  int g = blockIdx.x * 256 + threadIdx.x;
  if (g >= U_TOT) return;
  const float* w; int Cin, t, q, u, off; bool k3;
  if (g < U_B0) {
    int blk = g >> 10; w = w0; Cin = 256; k3 = false; t = 0; q = blk; u = g & 1023;
    off = OFF0 + blk * 8192;
  } else if (g < U_B0 + U_B) {
    int g1 = g - U_B0; int blk = g1 >> 10; w = w1; Cin = 256; k3 = true;
    t = blk >> 2; q = blk & 3; u = g1 & 1023; off = OFF1 + blk * 8192;
  } else if (g < U_B0 + 2*U_B) {
    int g1 = g - (U_B0 + U_B); int blk = g1 >> 10; w = w2; Cin = 256; k3 = true;
    t = blk >> 2; q = blk & 3; u = g1 & 1023; off = OFF2 + blk * 8192;
  } else if (g < U_B0 + 3*U_B) {
    int g1 = g - (U_B0 + 2*U_B); int blk = g1 >> 10; w = w3; Cin = 256; k3 = true;
    t = blk >> 2; q = blk & 3; u = g1 & 1023; off = OFF3 + blk * 8192;
  } else {
    int g1 = g - (U_B0 + 3*U_B); int blk = g1 >> 10; w = wp; Cin = 128; k3 = false;
    t = 0; q = blk; u = g1 & 1023; off = OFFP + blk * 8192;
  }
  int co = u >> 3, slot = u & 7;
  int sl = slot ^ (co & 7);           // logical 8-ci chunk stored at this physical slot
  int ci0 = q * 64 + sl * 8;
  int kh = k3 ? (t / 3) : 0, kw = k3 ? (t % 3) : 0;
  union { short8 s; u16 us[8]; } v;
  #pragma unroll
  for (int e = 0; e < 8; ++e) {
    int ci = ci0 + e;
    float wv = k3 ? w[((co * Cin + ci) * 3 + kh) * 3 + kw] : w[co * Cin + ci];
    v.us[e] = f2bf(wv);
  }
  *(short8*)(wpk + off + u * 8) = v.s;
}

// ---------- prep 3: BN scale/shift ----------
__global__ void k_bn(const float* g0,const float* b0,const float* m0,const float* v0,
                     const float* g1,const float* b1,const float* m1,const float* v1,
                     const float* g2,const float* b2,const float* m2,const float* v2,
                     const float* g3,const float* b3,const float* m3,const float* v3,
                     const float* gp,const float* bp,const float* mp,const float* vp,
                     float* __restrict__ bn) {
  int i = blockIdx.x * 256 + threadIdx.x;
  if (i >= 640) return;
  int t = i >> 7, co = i & 127;
  const float *G, *B, *M, *V;
  if      (t == 0) { G=g0; B=b0; M=m0; V=v0; }
  else if (t == 1) { G=g1; B=b1; M=m1; V=v1; }
  else if (t == 2) { G=g2; B=b2; M=m2; V=v2; }
  else if (t == 3) { G=g3; B=b3; M=m3; V=v3; }
  else             { G=gp; B=bp; M=mp; V=vp; }
  float s = G[co] * rsqrtf(V[co] + BN_EPS);
  bn[t * 256 + co]       = s;
  bn[t * 256 + 128 + co] = B[co] - M[co] * s;
}

// ---------- main: fused branch-conv + BN/ReLU + projection + BN/ReLU ----------
// LDS 48KB -> 3 blocks/CU. T14 async-split pipeline: prefetch step s+1 into regs
// during MFMA(s); raw s_barrier + lgkmcnt(0)-only waits keep globals in flight.
__global__ __launch_bounds__(256, 3)
void k_main(const u16* __restrict__ xb, const u16* __restrict__ wpk,
            const float* __restrict__ bn, float* __restrict__ out) {
  __shared__ __align__(16) u16 As[8192];    // 128 co x 64 k, swizzled by (co&7)
  __shared__ __align__(16) u16 BP[16384];   // branch phase: Bs = first 8192 (128px x 64k)
                                            // proj  phase: Ps = all (128px x 128ci)

  int tid = threadIdx.x;
  int bid = blockIdx.x;
  // XCD-locality: n = bid&7 pins each batch image's 2MB x-plane to one XCD L2
  int n = bid & 7;
  int rest = bid >> 3;
  int b = rest & 3;
  int tile = rest >> 2;                     // 0..31
  int i0 = tile * 2;
  int lane = tid & 63, wid = tid >> 6;
  int wm = wid >> 1, wn = wid & 1;
  int m16 = lane & 15, hh = lane >> 4;

  const u16* xg = xb + (size_t)n * (256 * 4096);
  int d = (b == 0) ? 0 : ((b == 1) ? 6 : ((b == 2) ? 12 : 18));
  int NS = ((b == 0) ? 1 : 9) * 4;
  int woff8 = ((b == 0) ? OFF0 : (b == 1) ? OFF1 : (b == 2) ? OFF2 : OFF3) / 8;

  const short8* wpk8 = (const short8*)wpk;
  short8* AsS8 = (short8*)As;
  short8* BsS8 = (short8*)BP;
  const short8* PsS8 = (const short8*)BP;

  floatx4 acc[4][4];
  #pragma unroll
  for (int a1 = 0; a1 < 4; ++a1)
    #pragma unroll
    for (int a2 = 0; a2 < 4; ++a2) acc[a1][a2] = (floatx4){0.f, 0.f, 0.f, 0.f};

  short8 ra[4];       // A prefetch regs
  uint32 rbv[16];     // B prefetch regs (dwords, px-pair x 8ci)
  bool inb0 = false, inb1 = false;

  // ---- prefetch step s into regs ----
  auto prefetch = [&](int s) {
    int abase = woff8 + s * 1024;
    #pragma unroll
    for (int w = 0; w < 4; ++w) ra[w] = wpk8[abase + w * 256 + tid];
    int t = s >> 2, q = s & 3;
    int di = d * (t / 3 - 1);
    int dj = d * (t % 3 - 1);
    #pragma unroll
    for (int pu = 0; pu < 2; ++pu) {
      int pidx = pu * 256 + tid;
      int cg = pidx >> 6;                 // 0..7
      int pp = pidx & 63;
      int row = pp >> 5;                  // 0..1
      int col0 = (pp & 31) * 2;           // even column
      int ii = i0 + row + di;
      int jj = col0 + dj;                 // even (d even) -> pair shares bounds
      bool inb = (ii >= 0) && (ii < 64) && (jj >= 0) && (jj < 64);
      if (pu == 0) inb0 = inb; else inb1 = inb;
      size_t offs = inb ? ((size_t)(q * 64 + cg * 8) * 4096 + (ii * 64 + jj)) : 0;
      const u16* src = xg + offs;
      #pragma unroll
      for (int e = 0; e < 8; ++e)
        rbv[pu * 8 + e] = *(const uint32*)(src + (size_t)e * 4096);
    }
  };

  prefetch(0);

  for (int s = 0; s < NS; ++s) {
    __builtin_amdgcn_s_barrier();          // all waves done reading LDS of step s-1
    // ---- ds_write staged regs (step s) ----
    #pragma unroll
    for (int w = 0; w < 4; ++w) AsS8[w * 256 + tid] = ra[w];
    #pragma unroll
    for (int pu = 0; pu < 2; ++pu) {
      bool inb = (pu == 0) ? inb0 : inb1;
      int pidx = pu * 256 + tid;
      int cg = pidx >> 6;
      int pp = pidx & 63;
      int row = pp >> 5;
      int col0 = (pp & 31) * 2;
      int px0 = row * 64 + col0;
      union { short8 s; u16 us[8]; } lo, hi;
      #pragma unroll
      for (int e = 0; e < 8; ++e) {
        uint32 vv = inb ? rbv[pu * 8 + e] : 0u;
        lo.us[e] = (u16)(vv & 0xffffu);
        hi.us[e] = (u16)(vv >> 16);
      }
      int sw = (px0 >> 1) & 7;
      BsS8[px0 * 8 + (cg ^ sw)] = lo.s;
      BsS8[(px0 + 1) * 8 + (cg ^ sw)] = hi.s;
    }
    // ---- issue prefetch for step s+1 (stays in flight across the barrier) ----
    if (s + 1 < NS) prefetch(s + 1);
    asm volatile("s_waitcnt lgkmcnt(0)" ::: "memory");   // ds_writes visible; vmcnt NOT drained
    __builtin_amdgcn_s_barrier();
    __builtin_amdgcn_sched_barrier(0);
    // ---- MFMA phase: 2 k-halves of 32 ----
    #pragma unroll
    for (int kk = 0; kk < 2; ++kk) {
      short8 af[4], bfr[4];
      #pragma unroll
      for (int f = 0; f < 4; ++f) {
        int row = wm * 64 + f * 16 + m16;
        af[f] = AsS8[row * 8 + ((kk * 4 + hh) ^ (row & 7))];
      }
      #pragma unroll
      for (int f = 0; f < 4; ++f) {
        int px = wn * 64 + f * 16 + m16;
        bfr[f] = BsS8[px * 8 + ((kk * 4 + hh) ^ ((px >> 1) & 7))];
      }
      #pragma unroll
      for (int fm = 0; fm < 4; ++fm)
        #pragma unroll
        for (int fn = 0; fn < 4; ++fn)
          acc[fm][fn] = __builtin_amdgcn_mfma_f32_16x16x32_bf16(
              af[fm], bfr[fn], acc[fm][fn], 0, 0, 0);
    }
  }

  // ---- branch BN + ReLU -> Ps (bf16), packed ds_write_b64 ----
  __syncthreads();                          // everyone done reading Bs/As
  #pragma unroll
  for (int fm = 0; fm < 4; ++fm) {
    int co_base = wm * 64 + fm * 16 + hh * 4;
    float sc[4], sh[4];
    #pragma unroll
    for (int r = 0; r < 4; ++r) {
      sc[r] = bn[b * 256 + co_base + r];
      sh[r] = bn[b * 256 + 128 + co_base + r];
    }
    #pragma unroll
    for (int fn = 0; fn < 4; ++fn) {
      int px = wn * 64 + fn * 16 + m16;
      int sw = (px >> 1) & 7;
      int slot = (co_base >> 3) ^ sw;
      union { shortx4 s4; u16 us[4]; } pk;
      #pragma unroll
      for (int r = 0; r < 4; ++r)
        pk.us[r] = f2bf(fmaxf(acc[fm][fn][r] * sc[r] + sh[r], 0.f));
      *(shortx4*)&BP[px * 128 + slot * 8 + (co_base & 7)] = pk.s4;
    }
  }

  // ---- projection GEMM: out128 x px128, K=128 ----
  floatx4 acc2[4][4];
  #pragma unroll
  for (int a1 = 0; a1 < 4; ++a1)
    #pragma unroll
    for (int a2 = 0; a2 < 4; ++a2) acc2[a1][a2] = (floatx4){0.f, 0.f, 0.f, 0.f};

  for (int q = 0; q < 2; ++q) {
    if (q == 1) __syncthreads();            // As reads (q=0) done before restage
    int abase = OFFP / 8 + q * 1024;
    #pragma unroll
    for (int w = 0; w < 4; ++w) AsS8[w * 256 + tid] = wpk8[abase + w * 256 + tid];
    __syncthreads();                        // As staged; (q=0) Ps writes visible too
    #pragma unroll
    for (int kk = 0; kk < 2; ++kk) {
      short8 af[4], bfr[4];
      #pragma unroll
      for (int f = 0; f < 4; ++f) {
        int row = wm * 64 + f * 16 + m16;
        af[f] = AsS8[row * 8 + ((kk * 4 + hh) ^ (row & 7))];
      }
      #pragma unroll
      for (int f = 0; f < 4; ++f) {
        int px = wn * 64 + f * 16 + m16;
        int slot = q * 8 + kk * 4 + hh;
        bfr[f] = PsS8[px * 16 + (slot ^ ((px >> 1) & 7))];
      }
      #pragma unroll
      for (int fm = 0; fm < 4; ++fm)
        #pragma unroll
        for (int fn = 0; fn < 4; ++fn)
          acc2[fm][fn] = __builtin_amdgcn_mfma_f32_16x16x32_bf16(
              af[fm], bfr[fn], acc2[fm][fn], 0, 0, 0);
    }
  }

  // ---- proj BN + ReLU -> interleaved store ----
  int rb2 = b >> 1, cb = b & 1;
  #pragma unroll
  for (int fm = 0; fm < 4; ++fm) {
    #pragma unroll
    for (int r = 0; r < 4; ++r) {
      int co = wm * 64 + fm * 16 + hh * 4 + r;
      float s  = bn[1024 + co];
      float sh = bn[1024 + 128 + co];
      #pragma unroll
      for (int fn = 0; fn < 4; ++fn) {
        int px = wn * 64 + fn * 16 + m16;
        int i = i0 + (px >> 6), j = px & 63;
        float v = fmaxf(acc2[fm][fn][r] * s + sh, 0.f);
        out[(((n * 128 + co) * 128) + (2 * i + rb2)) * 128 + (2 * j + cb)] = v;
      }
    }
  }
}

extern "C" void kernel_launch(void* const* d_in, const int* in_sizes, int n_in,
                              void* d_out, int out_size, void* d_ws, size_t ws_size,
                              hipStream_t stream) {
  const float* x  = (const float*)d_in[0];
  const float* w0 = (const float*)d_in[1];
  const float* w1 = (const float*)d_in[2];
  const float* w2 = (const float*)d_in[3];
  const float* w3 = (const float*)d_in[4];
  const float* wp = (const float*)d_in[5];

  u16* xbuf = (u16*)d_ws;                              // 8,388,608 shorts = 16 MiB
  u16* wpk  = (u16*)d_ws + 8388608;                    // 933,888 shorts
  float* bn = (float*)((char*)d_ws + 16777216 + 1867776);  // 5*256 floats

  k_xcvt<<<4096, 256, 0, stream>>>(x, xbuf, 1048576);
  k_wpack<<<456, 256, 0, stream>>>(w0, w1, w2, w3, wp, wpk);
  k_bn<<<3, 256, 0, stream>>>(
      (const float*)d_in[6],  (const float*)d_in[7],  (const float*)d_in[8],  (const float*)d_in[9],
      (const float*)d_in[10], (const float*)d_in[11], (const float*)d_in[12], (const float*)d_in[13],
      (const float*)d_in[14], (const float*)d_in[15], (const float*)d_in[16], (const float*)d_in[17],
      (const float*)d_in[18], (const float*)d_in[19], (const float*)d_in[20], (const float*)d_in[21],
      (const float*)d_in[22], (const float*)d_in[23], (const float*)d_in[24], (const float*)d_in[25],
      bn);
  k_main<<<1024, 256, 0, stream>>>(xbuf, wpk, bn, (float*)d_out);
}

// Round 4
// 109.243 us; speedup vs baseline: 1.3309x; 1.1078x over previous
//
#include <hip/hip_runtime.h>
#include <stdint.h>

typedef unsigned int uint32;
typedef uint16_t u16;
typedef short short8 __attribute__((ext_vector_type(8)));
typedef short shortx4 __attribute__((ext_vector_type(4)));
typedef float floatx4 __attribute__((ext_vector_type(4)));

#define BN_EPS 1e-5f

// ---- xb channel-last padded layout (shorts) ----
// xb[n][i][jp][ci]: n<8, i<64, jp<100 (jp = j+18, pads zeroed), ci<256
#define XROW 25600            // 100*256 shorts per (n,i) row
#define XPLANE 1638400        // 64*XROW shorts per n
#define XB_SHORTS 13107200    // 8 planes
#define ZROW_SHORTS 25600     // dedicated zero row for ii out-of-range

// wpack layout (shorts): per (branch, tap, ci-chunk-of-64) a 128x64 bf16 block,
// rows of 128B, 16B slots pre-XOR-swizzled by (co&7).
#define OFF0 0
#define OFF1 32768
#define OFF2 327680
#define OFF3 622592
#define OFFP 917504
#define WPK_SHORTS 933888
#define U_B0 4096
#define U_B  36864
#define U_TOT 116736

__device__ __forceinline__ u16 f2bf(float f) {
  uint32 u = __float_as_uint(f);
  u += 0x7fffu + ((u >> 16) & 1u);
  return (u16)(u >> 16);
}

// ---------- prep 1: x fp32 NCHW -> bf16 channel-last padded ----------
// grid 513: blocks 0..511 = (n,i); block 512 zeros the zero-row.
__global__ void k_xcvt(const float* __restrict__ x, u16* __restrict__ xb) {
  int bid = blockIdx.x, tid = threadIdx.x;
  if (bid == 512) {                       // zero the OOB fallback row
    uint32* z = (uint32*)(xb + XB_SHORTS);
    #pragma unroll
    for (int r = 0; r < 50; ++r) z[r * 256 + tid] = 0;
    return;
  }
  int n = bid >> 6, i = bid & 63;
  uint32* rw = (uint32*)(xb + (size_t)n * XPLANE + (size_t)i * XROW);
  // zero pad columns jp in [0,18) and [82,100): 36 cols * 128 u32 = 4608
  #pragma unroll
  for (int e = 0; e < 18; ++e) {
    int idx = e * 256 + tid;
    int colid = idx >> 7;                 // 0..35
    int jp = (colid < 18) ? colid : (colid + 64);
    rw[jp * 128 + (idx & 127)] = 0;
  }
  // interior: jp in [18,82)
  int ci2 = tid & 127, jh = tid >> 7;     // 2 ci per thread, j-half
  const float* xs = x + ((size_t)(n * 256 + 2 * ci2) * 64 + i) * 64 + jh * 32;
  #pragma unroll 4
  for (int j = 0; j < 32; ++j) {
    float f0 = xs[j];
    float f1 = xs[4096 + j];              // next ci plane = 64*64 floats
    uint32 pk = (uint32)f2bf(f0) | ((uint32)f2bf(f1) << 16);
    rw[(jh * 32 + j + 18) * 128 + ci2] = pk;
  }
}

// ---------- prep 2: pack + swizzle weights to bf16 ----------
__global__ void k_wpack(const float* __restrict__ w0, const float* __restrict__ w1,
                        const float* __restrict__ w2, const float* __restrict__ w3,
                        const float* __restrict__ wp, u16* __restrict__ wpk) {
  int g = blockIdx.x * 256 + threadIdx.x;
  if (g >= U_TOT) return;
  const float* w; int Cin, t, q, u, off; bool k3;
  if (g < U_B0) {
    int blk = g >> 10; w = w0; Cin = 256; k3 = false; t = 0; q = blk; u = g & 1023;
    off = OFF0 + blk * 8192;
  } else if (g < U_B0 + U_B) {
    int g1 = g - U_B0; int blk = g1 >> 10; w = w1; Cin = 256; k3 = true;
    t = blk >> 2; q = blk & 3; u = g1 & 1023; off = OFF1 + blk * 8192;
  } else if (g < U_B0 + 2*U_B) {
    int g1 = g - (U_B0 + U_B); int blk = g1 >> 10; w = w2; Cin = 256; k3 = true;
    t = blk >> 2; q = blk & 3; u = g1 & 1023; off = OFF2 + blk * 8192;
  } else if (g < U_B0 + 3*U_B) {
    int g1 = g - (U_B0 + 2*U_B); int blk = g1 >> 10; w = w3; Cin = 256; k3 = true;
    t = blk >> 2; q = blk & 3; u = g1 & 1023; off = OFF3 + blk * 8192;
  } else {
    int g1 = g - (U_B0 + 3*U_B); int blk = g1 >> 10; w = wp; Cin = 128; k3 = false;
    t = 0; q = blk; u = g1 & 1023; off = OFFP + blk * 8192;
  }
  int co = u >> 3, slot = u & 7;
  int sl = slot ^ (co & 7);           // logical 8-ci chunk stored at this physical slot
  int ci0 = q * 64 + sl * 8;
  int kh = k3 ? (t / 3) : 0, kw = k3 ? (t % 3) : 0;
  union { short8 s; u16 us[8]; } v;
  #pragma unroll
  for (int e = 0; e < 8; ++e) {
    int ci = ci0 + e;
    float wv = k3 ? w[((co * Cin + ci) * 3 + kh) * 3 + kw] : w[co * Cin + ci];
    v.us[e] = f2bf(wv);
  }
  *(short8*)(wpk + off + u * 8) = v.s;
}

// ---------- prep 3: BN scale/shift ----------
__global__ void k_bn(const float* g0,const float* b0,const float* m0,const float* v0,
                     const float* g1,const float* b1,const float* m1,const float* v1,
                     const float* g2,const float* b2,const float* m2,const float* v2,
                     const float* g3,const float* b3,const float* m3,const float* v3,
                     const float* gp,const float* bp,const float* mp,const float* vp,
                     float* __restrict__ bn) {
  int i = blockIdx.x * 256 + threadIdx.x;
  if (i >= 640) return;
  int t = i >> 7, co = i & 127;
  const float *G, *B, *M, *V;
  if      (t == 0) { G=g0; B=b0; M=m0; V=v0; }
  else if (t == 1) { G=g1; B=b1; M=m1; V=v1; }
  else if (t == 2) { G=g2; B=b2; M=m2; V=v2; }
  else if (t == 3) { G=g3; B=b3; M=m3; V=v3; }
  else             { G=gp; B=bp; M=mp; V=vp; }
  float s = G[co] * rsqrtf(V[co] + BN_EPS);
  bn[t * 256 + co]       = s;
  bn[t * 256 + 128 + co] = B[co] - M[co] * s;
}

// ---------- main: fused branch-conv + BN/ReLU + projection + BN/ReLU ----------
__global__ __launch_bounds__(256, 3)
void k_main(const u16* __restrict__ xb, const u16* __restrict__ wpk,
            const float* __restrict__ bn, float* __restrict__ out) {
  __shared__ __align__(16) u16 As[8192];    // 128 co x 64 k, swizzled by (co&7)
  __shared__ __align__(16) u16 BP[16384];   // branch: Bs = first 8192 (128px x 64k, swz px&7)
                                            // proj:   Ps = all (128px x 128ci)

  int tid = threadIdx.x;
  int bid = blockIdx.x;
  int n = bid & 7;                          // XCD-pinned batch image
  int rest = bid >> 3;
  int tile = rest >> 2;
  int b = (rest ^ (rest >> 5)) & 3;         // branch-balance across a CU's visits
  int i0 = tile * 2;
  int lane = tid & 63, wid = tid >> 6;
  int wm = wid >> 1, wn = wid & 1;
  int m16 = lane & 15, hh = lane >> 4;

  const u16* xg = xb + (size_t)n * XPLANE;
  const u16* zr = xb + XB_SHORTS;           // zero row
  int d = (b == 0) ? 0 : ((b == 1) ? 6 : ((b == 2) ? 12 : 18));
  int NS = ((b == 0) ? 1 : 9) * 4;
  int woff8 = ((b == 0) ? OFF0 : (b == 1) ? OFF1 : (b == 2) ? OFF2 : OFF3) / 8;

  const short8* wpk8 = (const short8*)wpk;
  short8* AsS8 = (short8*)As;
  short8* BsS8 = (short8*)BP;
  const short8* PsS8 = (const short8*)BP;

  floatx4 acc[4][4];
  #pragma unroll
  for (int a1 = 0; a1 < 4; ++a1)
    #pragma unroll
    for (int a2 = 0; a2 < 4; ++a2) acc[a1][a2] = (floatx4){0.f, 0.f, 0.f, 0.f};

  short8 ra[4];       // A prefetch regs
  short8 rb[4];       // B prefetch regs
  int cg = tid & 7, pxo = tid >> 3;         // B staging role: 8 ci-chunks x 32 px

  // ---- prefetch step s into regs (coalesced b128, channel-last) ----
  auto prefetch = [&](int s) {
    int abase = woff8 + s * 1024;
    #pragma unroll
    for (int w = 0; w < 4; ++w) ra[w] = wpk8[abase + w * 256 + tid];
    int t = s >> 2, q = s & 3;
    int di = d * (t / 3 - 1);
    int dj = d * (t % 3 - 1);
    #pragma unroll
    for (int k = 0; k < 4; ++k) {
      int px = k * 32 + pxo;
      int ii = i0 + (k >> 1) + di;          // uniform per k
      const u16* base = (ii >= 0 && ii < 64) ? (xg + ii * XROW) : zr;
      int jj = (px & 63) + 18 + dj;         // always in [0,100) thanks to padding
      rb[k] = *(const short8*)(base + jj * 256 + q * 64 + cg * 8);
    }
  };

  prefetch(0);

  for (int s = 0; s < NS; ++s) {
    __builtin_amdgcn_s_barrier();          // all waves done reading LDS of step s-1
    // ---- ds_write staged regs (step s) ----
    #pragma unroll
    for (int w = 0; w < 4; ++w) AsS8[w * 256 + tid] = ra[w];
    #pragma unroll
    for (int k = 0; k < 4; ++k) {
      int px = k * 32 + pxo;
      BsS8[px * 8 + (cg ^ (px & 7))] = rb[k];
    }
    // ---- issue prefetch for step s+1 (stays in flight across the barrier) ----
    if (s + 1 < NS) prefetch(s + 1);
    asm volatile("s_waitcnt lgkmcnt(0)" ::: "memory");   // ds_writes visible; vmcnt NOT drained
    __builtin_amdgcn_s_barrier();
    __builtin_amdgcn_sched_barrier(0);
    // ---- MFMA phase: 2 k-halves of 32 ----
    #pragma unroll
    for (int kk = 0; kk < 2; ++kk) {
      short8 af[4], bfr[4];
      #pragma unroll
      for (int f = 0; f < 4; ++f) {
        int row = wm * 64 + f * 16 + m16;
        af[f] = AsS8[row * 8 + ((kk * 4 + hh) ^ (row & 7))];
      }
      #pragma unroll
      for (int f = 0; f < 4; ++f) {
        int px = wn * 64 + f * 16 + m16;
        bfr[f] = BsS8[px * 8 + ((kk * 4 + hh) ^ (px & 7))];
      }
      #pragma unroll
      for (int fm = 0; fm < 4; ++fm)
        #pragma unroll
        for (int fn = 0; fn < 4; ++fn)
          acc[fm][fn] = __builtin_amdgcn_mfma_f32_16x16x32_bf16(
              af[fm], bfr[fn], acc[fm][fn], 0, 0, 0);
    }
  }

  // ---- branch BN + ReLU -> Ps (bf16) ----
  __syncthreads();                          // everyone done reading Bs/As
  #pragma unroll
  for (int fm = 0; fm < 4; ++fm) {
    int co_base = wm * 64 + fm * 16 + hh * 4;
    float sc[4], sh[4];
    #pragma unroll
    for (int r = 0; r < 4; ++r) {
      sc[r] = bn[b * 256 + co_base + r];
      sh[r] = bn[b * 256 + 128 + co_base + r];
    }
    #pragma unroll
    for (int fn = 0; fn < 4; ++fn) {
      int px = wn * 64 + fn * 16 + m16;
      int sw = (px >> 1) & 7;
      int slot = (co_base >> 3) ^ sw;
      union { shortx4 s4; u16 us[4]; } pk;
      #pragma unroll
      for (int r = 0; r < 4; ++r)
        pk.us[r] = f2bf(fmaxf(acc[fm][fn][r] * sc[r] + sh[r], 0.f));
      *(shortx4*)&BP[px * 128 + slot * 8 + (co_base & 7)] = pk.s4;
    }
  }

  // ---- projection GEMM: out128 x px128, K=128 ----
  floatx4 acc2[4][4];
  #pragma unroll
  for (int a1 = 0; a1 < 4; ++a1)
    #pragma unroll
    for (int a2 = 0; a2 < 4; ++a2) acc2[a1][a2] = (floatx4){0.f, 0.f, 0.f, 0.f};

  for (int q = 0; q < 2; ++q) {
    if (q == 1) __syncthreads();            // As reads (q=0) done before restage
    int abase = OFFP / 8 + q * 1024;
    #pragma unroll
    for (int w = 0; w < 4; ++w) AsS8[w * 256 + tid] = wpk8[abase + w * 256 + tid];
    __syncthreads();                        // As staged; (q=0) Ps writes visible too
    #pragma unroll
    for (int kk = 0; kk < 2; ++kk) {
      short8 af[4], bfr[4];
      #pragma unroll
      for (int f = 0; f < 4; ++f) {
        int row = wm * 64 + f * 16 + m16;
        af[f] = AsS8[row * 8 + ((kk * 4 + hh) ^ (row & 7))];
      }
      #pragma unroll
      for (int f = 0; f < 4; ++f) {
        int px = wn * 64 + f * 16 + m16;
        int slot = q * 8 + kk * 4 + hh;
        bfr[f] = PsS8[px * 16 + (slot ^ ((px >> 1) & 7))];
      }
      #pragma unroll
      for (int fm = 0; fm < 4; ++fm)
        #pragma unroll
        for (int fn = 0; fn < 4; ++fn)
          acc2[fm][fn] = __builtin_amdgcn_mfma_f32_16x16x32_bf16(
              af[fm], bfr[fn], acc2[fm][fn], 0, 0, 0);
    }
  }

  // ---- proj BN + ReLU -> interleaved store ----
  int rb2 = b >> 1, cb = b & 1;
  #pragma unroll
  for (int fm = 0; fm < 4; ++fm) {
    #pragma unroll
    for (int r = 0; r < 4; ++r) {
      int co = wm * 64 + fm * 16 + hh * 4 + r;
      float s  = bn[1024 + co];
      float sh = bn[1024 + 128 + co];
      #pragma unroll
      for (int fn = 0; fn < 4; ++fn) {
        int px = wn * 64 + fn * 16 + m16;
        int i = i0 + (px >> 6), j = px & 63;
        float v = fmaxf(acc2[fm][fn][r] * s + sh, 0.f);
        out[(((n * 128 + co) * 128) + (2 * i + rb2)) * 128 + (2 * j + cb)] = v;
      }
    }
  }
}

extern "C" void kernel_launch(void* const* d_in, const int* in_sizes, int n_in,
                              void* d_out, int out_size, void* d_ws, size_t ws_size,
                              hipStream_t stream) {
  const float* x  = (const float*)d_in[0];
  const float* w0 = (const float*)d_in[1];
  const float* w1 = (const float*)d_in[2];
  const float* w2 = (const float*)d_in[3];
  const float* w3 = (const float*)d_in[4];
  const float* wp = (const float*)d_in[5];

  u16* xbuf = (u16*)d_ws;                                   // XB + ZROW shorts
  u16* wpk  = (u16*)d_ws + (XB_SHORTS + ZROW_SHORTS);       // 933,888 shorts
  float* bn = (float*)((char*)d_ws + (size_t)(XB_SHORTS + ZROW_SHORTS + WPK_SHORTS) * 2);

  k_xcvt<<<513, 256, 0, stream>>>(x, xbuf);
  k_wpack<<<456, 256, 0, stream>>>(w0, w1, w2, w3, wp, wpk);
  k_bn<<<3, 256, 0, stream>>>(
      (const float*)d_in[6],  (const float*)d_in[7],  (const float*)d_in[8],  (const float*)d_in[9],
      (const float*)d_in[10], (const float*)d_in[11], (const float*)d_in[12], (const float*)d_in[13],
      (const float*)d_in[14], (const float*)d_in[15], (const float*)d_in[16], (const float*)d_in[17],
      (const float*)d_in[18], (const float*)d_in[19], (const float*)d_in[20], (const float*)d_in[21],
      (const float*)d_in[22], (const float*)d_in[23], (const float*)d_in[24], (const float*)d_in[25],
      bn);
  k_main<<<1024, 256, 0, stream>>>(xbuf, wpk, bn, (float*)d_out);
}

// Round 5
// 104.298 us; speedup vs baseline: 1.3939x; 1.0474x over previous
//
#include <hip/hip_runtime.h>
#include <stdint.h>

typedef unsigned int uint32;
typedef uint16_t u16;
typedef short short8 __attribute__((ext_vector_type(8)));
typedef short shortx4 __attribute__((ext_vector_type(4)));
typedef float floatx4 __attribute__((ext_vector_type(4)));

#define BN_EPS 1e-5f

// ---- xb channel-last padded layout (shorts) ----
// xb[n][i][jp][ci]: n<8, i<64, jp<100 (jp = j+18, pads zeroed), ci<256
#define XROW 25600            // 100*256 shorts per (n,i) row
#define XPLANE 1638400        // 64*XROW shorts per n
#define XB_SHORTS 13107200    // 8 planes
#define ZROW_SHORTS 25600     // dedicated zero row for ii out-of-range

// wpack layout (shorts): per (branch, tap, ci-chunk-of-64) a 128co x 64k bf16 block
// stored K-MAJOR: short8 unit u = slot*128 + co  (slot = k/8, 0..7). NO swizzle —
// A-fragments are loaded DIRECTLY from global (L1/L2-hot), coalesced 16 lanes x 16B.
#define OFF0 0
#define OFF1 32768
#define OFF2 327680
#define OFF3 622592
#define OFFP 917504
#define WPK_SHORTS 933888
#define U_B0 4096
#define U_B  36864
#define U_TOT 116736

__device__ __forceinline__ u16 f2bf(float f) {
  uint32 u = __float_as_uint(f);
  u += 0x7fffu + ((u >> 16) & 1u);
  return (u16)(u >> 16);
}

// ---------- prep 1: x fp32 NCHW -> bf16 channel-last padded ----------
__global__ void k_xcvt(const float* __restrict__ x, u16* __restrict__ xb) {
  int bid = blockIdx.x, tid = threadIdx.x;
  if (bid == 512) {                       // zero the OOB fallback row
    uint32* z = (uint32*)(xb + XB_SHORTS);
    #pragma unroll
    for (int r = 0; r < 50; ++r) z[r * 256 + tid] = 0;
    return;
  }
  int n = bid >> 6, i = bid & 63;
  uint32* rw = (uint32*)(xb + (size_t)n * XPLANE + (size_t)i * XROW);
  #pragma unroll
  for (int e = 0; e < 18; ++e) {
    int idx = e * 256 + tid;
    int colid = idx >> 7;                 // 0..35
    int jp = (colid < 18) ? colid : (colid + 64);
    rw[jp * 128 + (idx & 127)] = 0;
  }
  int ci2 = tid & 127, jh = tid >> 7;
  const float* xs = x + ((size_t)(n * 256 + 2 * ci2) * 64 + i) * 64 + jh * 32;
  #pragma unroll 4
  for (int j = 0; j < 32; ++j) {
    float f0 = xs[j];
    float f1 = xs[4096 + j];
    uint32 pk = (uint32)f2bf(f0) | ((uint32)f2bf(f1) << 16);
    rw[(jh * 32 + j + 18) * 128 + ci2] = pk;
  }
}

// ---------- prep 2: pack weights to bf16, k-major blocks ----------
__global__ void k_wpack(const float* __restrict__ w0, const float* __restrict__ w1,
                        const float* __restrict__ w2, const float* __restrict__ w3,
                        const float* __restrict__ wp, u16* __restrict__ wpk) {
  int g = blockIdx.x * 256 + threadIdx.x;
  if (g >= U_TOT) return;
  const float* w; int Cin, t, q, u, off; bool k3;
  if (g < U_B0) {
    int blk = g >> 10; w = w0; Cin = 256; k3 = false; t = 0; q = blk; u = g & 1023;
    off = OFF0 + blk * 8192;
  } else if (g < U_B0 + U_B) {
    int g1 = g - U_B0; int blk = g1 >> 10; w = w1; Cin = 256; k3 = true;
    t = blk >> 2; q = blk & 3; u = g1 & 1023; off = OFF1 + blk * 8192;
  } else if (g < U_B0 + 2*U_B) {
    int g1 = g - (U_B0 + U_B); int blk = g1 >> 10; w = w2; Cin = 256; k3 = true;
    t = blk >> 2; q = blk & 3; u = g1 & 1023; off = OFF2 + blk * 8192;
  } else if (g < U_B0 + 3*U_B) {
    int g1 = g - (U_B0 + 2*U_B); int blk = g1 >> 10; w = w3; Cin = 256; k3 = true;
    t = blk >> 2; q = blk & 3; u = g1 & 1023; off = OFF3 + blk * 8192;
  } else {
    int g1 = g - (U_B0 + 3*U_B); int blk = g1 >> 10; w = wp; Cin = 128; k3 = false;
    t = 0; q = blk; u = g1 & 1023; off = OFFP + blk * 8192;
  }
  int slot = u >> 7, co = u & 127;        // k-major
  int ci0 = q * 64 + slot * 8;
  int kh = k3 ? (t / 3) : 0, kw = k3 ? (t % 3) : 0;
  union { short8 s; u16 us[8]; } v;
  #pragma unroll
  for (int e = 0; e < 8; ++e) {
    int ci = ci0 + e;
    float wv = k3 ? w[((co * Cin + ci) * 3 + kh) * 3 + kw] : w[co * Cin + ci];
    v.us[e] = f2bf(wv);
  }
  *(short8*)(wpk + off + u * 8) = v.s;
}

// ---------- prep 3: BN scale/shift ----------
__global__ void k_bn(const float* g0,const float* b0,const float* m0,const float* v0,
                     const float* g1,const float* b1,const float* m1,const float* v1,
                     const float* g2,const float* b2,const float* m2,const float* v2,
                     const float* g3,const float* b3,const float* m3,const float* v3,
                     const float* gp,const float* bp,const float* mp,const float* vp,
                     float* __restrict__ bn) {
  int i = blockIdx.x * 256 + threadIdx.x;
  if (i >= 640) return;
  int t = i >> 7, co = i & 127;
  const float *G, *B, *M, *V;
  if      (t == 0) { G=g0; B=b0; M=m0; V=v0; }
  else if (t == 1) { G=g1; B=b1; M=m1; V=v1; }
  else if (t == 2) { G=g2; B=b2; M=m2; V=v2; }
  else if (t == 3) { G=g3; B=b3; M=m3; V=v3; }
  else             { G=gp; B=bp; M=mp; V=vp; }
  float s = G[co] * rsqrtf(V[co] + BN_EPS);
  bn[t * 256 + co]       = s;
  bn[t * 256 + 128 + co] = B[co] - M[co] * s;
}

// ---------- main: fused branch-conv + BN/ReLU + projection + BN/ReLU ----------
// A (weights) read DIRECTLY from global per fragment (L1/L2-hot, coalesced);
// only B goes through LDS. LDS = 32KB (Bs 16KB during conv, Ps 32KB for proj).
__global__ __launch_bounds__(256, 3)
void k_main(const u16* __restrict__ xb, const u16* __restrict__ wpk,
            const float* __restrict__ bn, float* __restrict__ out) {
  __shared__ __align__(16) u16 BP[16384];   // conv: Bs = first 8192 (128px x 64k, swz px&7)
                                            // proj: Ps = all (128px x 128ci)

  int tid = threadIdx.x;
  int bid = blockIdx.x;
  int n = bid & 7;                          // XCD-pinned batch image
  int rest = bid >> 3;
  int tile = rest >> 2;
  int b = (rest ^ (rest >> 5)) & 3;         // branch-balance across a CU's visits
  int i0 = tile * 2;
  int lane = tid & 63, wid = tid >> 6;
  int wm = wid >> 1, wn = wid & 1;
  int m16 = lane & 15, hh = lane >> 4;

  const u16* xg = xb + (size_t)n * XPLANE;
  const u16* zr = xb + XB_SHORTS;           // zero row
  int d = (b == 0) ? 0 : ((b == 1) ? 6 : ((b == 2) ? 12 : 18));
  int NS = ((b == 0) ? 1 : 9) * 4;
  int woff8 = ((b == 0) ? OFF0 : (b == 1) ? OFF1 : (b == 2) ? OFF2 : OFF3) / 8;

  const short8* wpk8 = (const short8*)wpk;
  short8* BsS8 = (short8*)BP;
  const short8* PsS8 = (const short8*)BP;

  floatx4 acc[4][4];
  #pragma unroll
  for (int a1 = 0; a1 < 4; ++a1)
    #pragma unroll
    for (int a2 = 0; a2 < 4; ++a2) acc[a1][a2] = (floatx4){0.f, 0.f, 0.f, 0.f};

  short8 rb[4];                             // B prefetch regs
  int cg = tid & 7, pxo = tid >> 3;         // B staging role: 8 ci-chunks x 32 px
  int arow = wm * 64 + m16;                 // A-fragment row base (this lane)

  // ---- prefetch B for step s into regs (coalesced b128, channel-last) ----
  auto prefetchB = [&](int s) {
    int t = s >> 2, q = s & 3;
    int di = d * (t / 3 - 1);
    int dj = d * (t % 3 - 1);
    #pragma unroll
    for (int k = 0; k < 4; ++k) {
      int px = k * 32 + pxo;
      int ii = i0 + (k >> 1) + di;
      const u16* base = (ii >= 0 && ii < 64) ? (xg + ii * XROW) : zr;
      int jj = (px & 63) + 18 + dj;
      rb[k] = *(const short8*)(base + jj * 256 + q * 64 + cg * 8);
    }
  };

  prefetchB(0);

  for (int s = 0; s < NS; ++s) {
    __builtin_amdgcn_s_barrier();          // all waves done reading Bs of step s-1
    // ---- ds_write staged B regs (step s): 4 x ds_write_b128 ----
    #pragma unroll
    for (int k = 0; k < 4; ++k) {
      int px = k * 32 + pxo;
      BsS8[px * 8 + (cg ^ (px & 7))] = rb[k];
    }
    // ---- A fragments for step s, direct from global (L1/L2-hot) ----
    short8 af[2][4];
    {
      int abase = woff8 + s * 1024;
      #pragma unroll
      for (int kk = 0; kk < 2; ++kk)
        #pragma unroll
        for (int f = 0; f < 4; ++f)
          af[kk][f] = wpk8[abase + (kk * 4 + hh) * 128 + arow + f * 16];
    }
    // ---- issue B prefetch for step s+1 (stays in flight across the barrier) ----
    if (s + 1 < NS) prefetchB(s + 1);
    asm volatile("s_waitcnt lgkmcnt(0)" ::: "memory");   // ds_writes visible; vmcnt NOT drained
    __builtin_amdgcn_s_barrier();
    // ---- MFMA phase: 2 k-halves of 32 ----
    #pragma unroll
    for (int kk = 0; kk < 2; ++kk) {
      short8 bfr[4];
      #pragma unroll
      for (int f = 0; f < 4; ++f) {
        int px = wn * 64 + f * 16 + m16;
        bfr[f] = BsS8[px * 8 + ((kk * 4 + hh) ^ (px & 7))];
      }
      #pragma unroll
      for (int fm = 0; fm < 4; ++fm)
        #pragma unroll
        for (int fn = 0; fn < 4; ++fn)
          acc[fm][fn] = __builtin_amdgcn_mfma_f32_16x16x32_bf16(
              af[kk][fm], bfr[fn], acc[fm][fn], 0, 0, 0);
    }
  }

  // ---- branch BN + ReLU -> Ps (bf16) ----
  __syncthreads();                          // everyone done reading Bs
  #pragma unroll
  for (int fm = 0; fm < 4; ++fm) {
    int co_base = wm * 64 + fm * 16 + hh * 4;
    float sc[4], sh[4];
    #pragma unroll
    for (int r = 0; r < 4; ++r) {
      sc[r] = bn[b * 256 + co_base + r];
      sh[r] = bn[b * 256 + 128 + co_base + r];
    }
    #pragma unroll
    for (int fn = 0; fn < 4; ++fn) {
      int px = wn * 64 + fn * 16 + m16;
      int sw = (px >> 1) & 7;
      int slot = (co_base >> 3) ^ sw;
      union { shortx4 s4; u16 us[4]; } pk;
      #pragma unroll
      for (int r = 0; r < 4; ++r)
        pk.us[r] = f2bf(fmaxf(acc[fm][fn][r] * sc[r] + sh[r], 0.f));
      *(shortx4*)&BP[px * 128 + slot * 8 + (co_base & 7)] = pk.s4;
    }
  }

  // ---- projection GEMM: out128 x px128, K=128 (A direct from global) ----
  floatx4 acc2[4][4];
  #pragma unroll
  for (int a1 = 0; a1 < 4; ++a1)
    #pragma unroll
    for (int a2 = 0; a2 < 4; ++a2) acc2[a1][a2] = (floatx4){0.f, 0.f, 0.f, 0.f};

  __syncthreads();                          // Ps fully written
  #pragma unroll
  for (int q = 0; q < 2; ++q) {
    #pragma unroll
    for (int kk = 0; kk < 2; ++kk) {
      short8 af2[4], bfr[4];
      #pragma unroll
      for (int f = 0; f < 4; ++f)
        af2[f] = wpk8[OFFP / 8 + q * 1024 + (kk * 4 + hh) * 128 + arow + f * 16];
      #pragma unroll
      for (int f = 0; f < 4; ++f) {
        int px = wn * 64 + f * 16 + m16;
        int slot = q * 8 + kk * 4 + hh;
        bfr[f] = PsS8[px * 16 + (slot ^ ((px >> 1) & 7))];
      }
      #pragma unroll
      for (int fm = 0; fm < 4; ++fm)
        #pragma unroll
        for (int fn = 0; fn < 4; ++fn)
          acc2[fm][fn] = __builtin_amdgcn_mfma_f32_16x16x32_bf16(
              af2[fm], bfr[fn], acc2[fm][fn], 0, 0, 0);
    }
  }

  // ---- proj BN + ReLU -> interleaved store ----
  int rb2 = b >> 1, cb = b & 1;
  #pragma unroll
  for (int fm = 0; fm < 4; ++fm) {
    #pragma unroll
    for (int r = 0; r < 4; ++r) {
      int co = wm * 64 + fm * 16 + hh * 4 + r;
      float s  = bn[1024 + co];
      float sh = bn[1024 + 128 + co];
      #pragma unroll
      for (int fn = 0; fn < 4; ++fn) {
        int px = wn * 64 + fn * 16 + m16;
        int i = i0 + (px >> 6), j = px & 63;
        float v = fmaxf(acc2[fm][fn][r] * s + sh, 0.f);
        out[(((n * 128 + co) * 128) + (2 * i + rb2)) * 128 + (2 * j + cb)] = v;
      }
    }
  }
}

extern "C" void kernel_launch(void* const* d_in, const int* in_sizes, int n_in,
                              void* d_out, int out_size, void* d_ws, size_t ws_size,
                              hipStream_t stream) {
  const float* x  = (const float*)d_in[0];
  const float* w0 = (const float*)d_in[1];
  const float* w1 = (const float*)d_in[2];
  const float* w2 = (const float*)d_in[3];
  const float* w3 = (const float*)d_in[4];
  const float* wp = (const float*)d_in[5];

  u16* xbuf = (u16*)d_ws;                                   // XB + ZROW shorts
  u16* wpk  = (u16*)d_ws + (XB_SHORTS + ZROW_SHORTS);       // 933,888 shorts
  float* bn = (float*)((char*)d_ws + (size_t)(XB_SHORTS + ZROW_SHORTS + WPK_SHORTS) * 2);

  k_xcvt<<<513, 256, 0, stream>>>(x, xbuf);
  k_wpack<<<456, 256, 0, stream>>>(w0, w1, w2, w3, wp, wpk);
  k_bn<<<3, 256, 0, stream>>>(
      (const float*)d_in[6],  (const float*)d_in[7],  (const float*)d_in[8],  (const float*)d_in[9],
      (const float*)d_in[10], (const float*)d_in[11], (const float*)d_in[12], (const float*)d_in[13],
      (const float*)d_in[14], (const float*)d_in[15], (const float*)d_in[16], (const float*)d_in[17],
      (const float*)d_in[18], (const float*)d_in[19], (const float*)d_in[20], (const float*)d_in[21],
      (const float*)d_in[22], (const float*)d_in[23], (const float*)d_in[24], (const float*)d_in[25],
      bn);
  k_main<<<1024, 256, 0, stream>>>(xbuf, wpk, bn, (float*)d_out);
}